// Round 3
// baseline (2277.044 us; speedup 1.0000x reference)
//
#include <hip/hip_runtime.h>

#define DFEAT 32
#define VB 512          // vertices per bucket (power of 2)
#define VB_SHIFT 9
#define NREP 4          // cursor replicas per bucket (spread atomic contention)
#define ACCS 33         // LDS accumulator stride in floats (pad breaks bank pattern)
#define MAXC 16384      // max bucket*replica counters supported

// ============ K1: histogram of (bucket, replica) occupancy ============
// Replica of half-edge i is (i>>2)&3 — consistent between K1 and K3 because
// both process element i of int4 t (i = 4t+j -> replica = t&3).
__global__ void he2v_bhist(const int* __restrict__ ids,
                           int* __restrict__ counts, int n_he) {
    long tid = (long)blockIdx.x * blockDim.x + threadIdx.x;
    long stride = (long)gridDim.x * blockDim.x;
    long n4 = n_he >> 2;
    for (long t = tid; t < n4; t += stride) {
        int4 w = ((const int4*)ids)[t];
        int rep = (int)(t & 3);
        atomicAdd(&counts[(w.x >> VB_SHIFT) * NREP + rep], 1);
        atomicAdd(&counts[(w.y >> VB_SHIFT) * NREP + rep], 1);
        atomicAdd(&counts[(w.z >> VB_SHIFT) * NREP + rep], 1);
        atomicAdd(&counts[(w.w >> VB_SHIFT) * NREP + rep], 1);
    }
    int rem = n_he & 3;
    if (tid < rem) {
        int i = (int)(n4 << 2) + (int)tid;
        int rep = (i >> 2) & 3;
        atomicAdd(&counts[(ids[i] >> VB_SHIFT) * NREP + rep], 1);
    }
}

// ============ K2: exclusive scan of counters (single block) ============
// Writes base[i] and cursor[i]; base[n] = total (sentinel for bucket ends).
__global__ void he2v_bscan(const int* __restrict__ counts,
                           int* __restrict__ base,
                           int* __restrict__ cursor, int n) {
    __shared__ int buf[1024];
    __shared__ int carry_s;
    int t = threadIdx.x;
    if (t == 0) carry_s = 0;
    __syncthreads();
    for (int tile = 0; tile < n; tile += 1024) {
        int i = tile + t;
        int v = (i < n) ? counts[i] : 0;
        buf[t] = v;
        __syncthreads();
        for (int off = 1; off < 1024; off <<= 1) {
            int tv = (t >= off) ? buf[t - off] : 0;
            __syncthreads();
            buf[t] += tv;
            __syncthreads();
        }
        int incl = buf[t];
        int carry = carry_s;
        __syncthreads();
        if (i < n) { int e = carry + incl - v; base[i] = e; cursor[i] = e; }
        if (t == 1023) carry_s = carry + incl;
        __syncthreads();
    }
    if (t == 0) base[n] = carry_s;
}

// ============ K3: append (he, v) pairs into bucket regions ============
__global__ void he2v_pairs(const int* __restrict__ ids,
                           int* __restrict__ cursor,
                           int2* __restrict__ pairs, int n_he) {
    long tid = (long)blockIdx.x * blockDim.x + threadIdx.x;
    long stride = (long)gridDim.x * blockDim.x;
    long n4 = n_he >> 2;
    for (long t = tid; t < n4; t += stride) {
        int4 w = ((const int4*)ids)[t];
        int rep = (int)(t & 3);
        int i0 = (int)(t << 2);
        int p;
        p = atomicAdd(&cursor[(w.x >> VB_SHIFT) * NREP + rep], 1);
        pairs[p] = make_int2(i0, w.x);
        p = atomicAdd(&cursor[(w.y >> VB_SHIFT) * NREP + rep], 1);
        pairs[p] = make_int2(i0 + 1, w.y);
        p = atomicAdd(&cursor[(w.z >> VB_SHIFT) * NREP + rep], 1);
        pairs[p] = make_int2(i0 + 2, w.z);
        p = atomicAdd(&cursor[(w.w >> VB_SHIFT) * NREP + rep], 1);
        pairs[p] = make_int2(i0 + 3, w.w);
    }
    int rem = n_he & 3;
    if (tid < rem) {
        int i = (int)(n4 << 2) + (int)tid;
        int rep = (i >> 2) & 3;
        int v = ids[i];
        int p = atomicAdd(&cursor[(v >> VB_SHIFT) * NREP + rep], 1);
        pairs[p] = make_int2(i, v);
    }
}

// ============ K4: per-bucket LDS accumulation + divide + write ============
// Block b owns vertices [b*VB, (b+1)*VB). Streams its pair segment, reads
// each x row once (random 128B), LDS-atomic accumulates into a padded tile,
// then writes the output slice coalesced exactly once. No global fp32 atomics.
__global__ __launch_bounds__(512)
void he2v_accum(const float* __restrict__ x,
                const int2* __restrict__ pairs,
                const int* __restrict__ base,
                float* __restrict__ out, int n_v) {
    __shared__ float acc[VB * ACCS];   // 512*33*4 = 67.6 KB
    __shared__ int   val[VB];          // 2 KB
    int b = blockIdx.x;
    int t = threadIdx.x;               // 512 threads = 64 groups of 8
    for (int i = t; i < VB * ACCS; i += 512) acc[i] = 0.0f;
    for (int i = t; i < VB; i += 512) val[i] = 0;
    __syncthreads();

    int start = base[b * NREP];
    int end   = base[(b + 1) * NREP];
    int cnt   = end - start;
    int gidx = t >> 3, q = t & 7;
    const float4* x4 = (const float4*)x;

    int r = gidx;
    // unroll-2: two independent random x-loads in flight per group
    for (; r + 64 < cnt; r += 128) {
        int2 p0 = pairs[start + r];
        int2 p1 = pairs[start + r + 64];
        float4 x0 = x4[(long)p0.x * 8 + q];
        float4 x1 = x4[(long)p1.x * 8 + q];
        int v0 = p0.y & (VB - 1);
        float* a0 = &acc[v0 * ACCS + q * 4];
        atomicAdd(a0 + 0, x0.x); atomicAdd(a0 + 1, x0.y);
        atomicAdd(a0 + 2, x0.z); atomicAdd(a0 + 3, x0.w);
        if (q == 0) atomicAdd(&val[v0], 1);
        int v1 = p1.y & (VB - 1);
        float* a1 = &acc[v1 * ACCS + q * 4];
        atomicAdd(a1 + 0, x1.x); atomicAdd(a1 + 1, x1.y);
        atomicAdd(a1 + 2, x1.z); atomicAdd(a1 + 3, x1.w);
        if (q == 0) atomicAdd(&val[v1], 1);
    }
    if (r < cnt) {
        int2 p0 = pairs[start + r];
        float4 x0 = x4[(long)p0.x * 8 + q];
        int v0 = p0.y & (VB - 1);
        float* a0 = &acc[v0 * ACCS + q * 4];
        atomicAdd(a0 + 0, x0.x); atomicAdd(a0 + 1, x0.y);
        atomicAdd(a0 + 2, x0.z); atomicAdd(a0 + 3, x0.w);
        if (q == 0) atomicAdd(&val[v0], 1);
    }
    __syncthreads();

    // epilogue: each 8-lane group writes one vertex row per step (coalesced)
    float4* out4 = (float4*)out;
    for (int vl = gidx; vl < VB; vl += 64) {
        long v = ((long)b << VB_SHIFT) + vl;
        if (v >= n_v) break;
        int c = val[vl];
        float inv = 1.0f / (float)(c > 0 ? c : 1);
        const float* a = &acc[vl * ACCS + q * 4];
        float4 o;
        o.x = a[0] * inv; o.y = a[1] * inv;
        o.z = a[2] * inv; o.w = a[3] * inv;
        out4[v * 8 + q] = o;
    }
}

// ===================== Fallback: atomic scatter ============================
__global__ void he2v_scatter(const float* __restrict__ x,
                             const int* __restrict__ ids,
                             float* __restrict__ out,
                             float* __restrict__ val,
                             int n_he) {
    long tid = (long)blockIdx.x * blockDim.x + threadIdx.x;
    long stride = (long)gridDim.x * blockDim.x;
    long total = (long)n_he * 8;
    for (long t = tid; t < total; t += stride) {
        int row = (int)(t >> 3);
        int q   = (int)(t & 7);
        int v   = ids[row];
        float4 xv = ((const float4*)x)[(long)row * 8 + q];
        float* dst = out + (long)v * DFEAT + q * 4;
        atomicAdd(dst + 0, xv.x);
        atomicAdd(dst + 1, xv.y);
        atomicAdd(dst + 2, xv.z);
        atomicAdd(dst + 3, xv.w);
        if (q == 0) atomicAdd(val + v, 1.0f);
    }
}

__global__ void he2v_divide(float* __restrict__ out,
                            const float* __restrict__ val,
                            int n_v) {
    long tid = (long)blockIdx.x * blockDim.x + threadIdx.x;
    long total = (long)n_v * 8;
    if (tid >= total) return;
    int v = (int)(tid >> 3);
    float s = val[v];
    if (s < 1.0f) s = 1.0f;
    float4 o = ((float4*)out)[tid];
    o.x /= s; o.y /= s; o.z /= s; o.w /= s;
    ((float4*)out)[tid] = o;
}

extern "C" void kernel_launch(void* const* d_in, const int* in_sizes, int n_in,
                              void* d_out, int out_size, void* d_ws, size_t ws_size,
                              hipStream_t stream) {
    const float* x  = (const float*)d_in[0];
    const int* ids  = (const int*)d_in[1];
    int n_he = in_sizes[0] / DFEAT;
    int n_v  = out_size / DFEAT;
    float* out = (float*)d_out;

    int nb  = (n_v + VB - 1) / VB;     // buckets
    int nc  = nb * NREP;               // replicated counters
    // ws ints: counts[nc] | base[nc+1] | cursor[nc] | pad | pairs[n_he] (int2)
    size_t headInts = ((size_t)3 * nc + 1 + 1) & ~(size_t)1;
    size_t need = headInts * sizeof(int) + (size_t)n_he * sizeof(int2);

    if (nc <= MAXC && ws_size >= need) {
        int* counts = (int*)d_ws;
        int* base   = counts + nc;
        int* cursor = base + nc + 1;
        int2* pairs = (int2*)((int*)d_ws + headInts);

        hipMemsetAsync(counts, 0, (size_t)nc * sizeof(int), stream);
        he2v_bhist<<<1024, 256, 0, stream>>>(ids, counts, n_he);
        he2v_bscan<<<1, 1024, 0, stream>>>(counts, base, cursor, nc);
        he2v_pairs<<<2048, 256, 0, stream>>>(ids, cursor, pairs, n_he);
        he2v_accum<<<nb, 512, 0, stream>>>(x, pairs, base, out, n_v);
    } else {
        float* val = (float*)d_ws;
        hipMemsetAsync(out, 0, (size_t)out_size * sizeof(float), stream);
        hipMemsetAsync(val, 0, (size_t)n_v * sizeof(float), stream);
        he2v_scatter<<<8192, 256, 0, stream>>>(x, ids, out, val, n_he);
        long total = (long)n_v * 8;
        int blocks = (int)((total + 255) / 256);
        he2v_divide<<<blocks, 256, 0, stream>>>(out, val, n_v);
    }
}

// Round 4
// 1986.208 us; speedup vs baseline: 1.1464x; 1.1464x over previous
//
#include <hip/hip_runtime.h>

#define DFEAT 32
#define VB_C 2048        // vertices per coarse bucket
#define VB_C_SHIFT 11
#define NC_MAX 512       // max coarse buckets supported (512*2048 = 1,048,576 vertices)
#define CREP 64          // cursor replicas per coarse bucket
#define CHUNK 8192       // ids per partition block
#define VT 256           // vertices per accum tile (2048/256 = 8 parts)
#define ACCS 33          // LDS accumulator stride (pad breaks bank pattern)

// ============ K1: coarse histogram via block-local LDS hist ============
// One block per CHUNK of ids. LDS histogram (489 bins), then one global
// fire-and-forget atomic per nonzero bin into counts[b*CREP + rep].
// rep = blockIdx % CREP -- MUST match he2v_part exactly (same grid).
__global__ __launch_bounds__(512)
void he2v_chist(const int* __restrict__ ids, int* __restrict__ counts,
                int n_he) {
    __shared__ int sHist[NC_MAX];
    int t = threadIdx.x;
    long cbase = (long)blockIdx.x * CHUNK;
    int n = (int)((long)n_he - cbase < CHUNK ? (long)n_he - cbase : CHUNK);
    int rep = blockIdx.x & (CREP - 1);
    for (int i = t; i < NC_MAX; i += 512) sHist[i] = 0;
    __syncthreads();
    for (int i = t; i < n; i += 512)
        atomicAdd(&sHist[ids[cbase + i] >> VB_C_SHIFT], 1);
    __syncthreads();
    for (int b = t; b < NC_MAX; b += 512) {
        int h = sHist[b];
        if (h) atomicAdd(&counts[b * CREP + rep], h);
    }
}

// ============ K2: exclusive scan (single block, serial tiles) ============
// base[i] and cursor[i] = exclusive prefix; base[n] = total sentinel.
__global__ void he2v_bscan(const int* __restrict__ counts,
                           int* __restrict__ base,
                           int* __restrict__ cursor, int n) {
    __shared__ int buf[1024];
    __shared__ int carry_s;
    int t = threadIdx.x;
    if (t == 0) carry_s = 0;
    __syncthreads();
    for (int tile = 0; tile < n; tile += 1024) {
        int i = tile + t;
        int v = (i < n) ? counts[i] : 0;
        buf[t] = v;
        __syncthreads();
        for (int off = 1; off < 1024; off <<= 1) {
            int tv = (t >= off) ? buf[t - off] : 0;
            __syncthreads();
            buf[t] += tv;
            __syncthreads();
        }
        int incl = buf[t];
        int carry = carry_s;
        __syncthreads();
        if (i < n) { int e = carry + incl - v; base[i] = e; cursor[i] = e; }
        if (t == 1023) carry_s = carry + incl;
        __syncthreads();
    }
    if (t == 0) base[n] = carry_s;
}

// ============ K3: partition (he,v) pairs into coarse buckets ============
// Per chunk: LDS-stage ids, LDS hist, ONE cursor atomic per bucket to
// reserve a contiguous run, then rank+write. Runs (~134B) are written
// entirely by this block -> line-dense stores, no cross-XCD bouncing.
__global__ __launch_bounds__(512)
void he2v_part(const int* __restrict__ ids, int* __restrict__ cursor,
               int2* __restrict__ pairs, int n_he) {
    __shared__ int sHist[NC_MAX];
    __shared__ int sBase[NC_MAX];
    __shared__ int sIds[CHUNK];   // 32 KB
    int t = threadIdx.x;
    long cbase = (long)blockIdx.x * CHUNK;
    int n = (int)((long)n_he - cbase < CHUNK ? (long)n_he - cbase : CHUNK);
    int rep = blockIdx.x & (CREP - 1);
    for (int i = t; i < NC_MAX; i += 512) sHist[i] = 0;
    for (int i = t; i < n; i += 512) sIds[i] = ids[cbase + i];
    __syncthreads();
    for (int i = t; i < n; i += 512)
        atomicAdd(&sHist[sIds[i] >> VB_C_SHIFT], 1);
    __syncthreads();
    for (int b = t; b < NC_MAX; b += 512) {
        int h = sHist[b];
        sBase[b] = h ? atomicAdd(&cursor[b * CREP + rep], h) : 0;
        sHist[b] = 0;   // reuse as rank counter
    }
    __syncthreads();
    for (int i = t; i < n; i += 512) {
        int v = sIds[i];
        int b = v >> VB_C_SHIFT;
        int r = atomicAdd(&sHist[b], 1);
        pairs[(long)sBase[b] + r] = make_int2((int)(cbase + i), v);
    }
}

// ============ K4: per-tile LDS accumulation + divide + write ============
// 8 blocks per coarse bucket; block owns a 256-vertex tile (33.8KB LDS ->
// 4 blocks/CU, full occupancy). Scans the bucket's sequential pair list
// with a membership filter; active pairs read x once (random 128B via 8
// lanes) and LDS-atomic accumulate. Output written exactly once.
__global__ __launch_bounds__(512)
void he2v_accum(const float* __restrict__ x,
                const int2* __restrict__ pairs,
                const int* __restrict__ base,
                float* __restrict__ out, int n_v) {
    __shared__ float acc[VT * ACCS];   // 256*33*4 = 33.8 KB
    __shared__ int   val[VT];
    int blk = blockIdx.x;
    int c = blk >> 3, part = blk & 7;
    int t = threadIdx.x;
    for (int i = t; i < VT * ACCS; i += 512) acc[i] = 0.0f;
    if (t < VT) val[t] = 0;
    __syncthreads();

    int start = base[c * CREP];
    int cnt   = base[(c + 1) * CREP] - start;
    int g = t >> 3, q = t & 7;         // 64 groups of 8 lanes
    const float4* x4 = (const float4*)x;

#define PROC(P)  do {                                                   \
        int voff = (P).y & (VB_C - 1);                                  \
        if ((voff >> 8) == part) {                                      \
            float4 xv = x4[(long)(P).x * 8 + q];                        \
            int to = voff & (VT - 1);                                   \
            float* a = &acc[to * ACCS + q * 4];                         \
            atomicAdd(a + 0, xv.x); atomicAdd(a + 1, xv.y);             \
            atomicAdd(a + 2, xv.z); atomicAdd(a + 3, xv.w);             \
            if (q == 0) atomicAdd(&val[to], 1);                         \
        } } while (0)

    int r = g;
    for (; r + 192 < cnt; r += 256) {
        int2 p0 = pairs[start + r];
        int2 p1 = pairs[start + r + 64];
        int2 p2 = pairs[start + r + 128];
        int2 p3 = pairs[start + r + 192];
        PROC(p0); PROC(p1); PROC(p2); PROC(p3);
    }
    for (; r < cnt; r += 64) {
        int2 p0 = pairs[start + r];
        PROC(p0);
    }
#undef PROC
    __syncthreads();

    float4* out4 = (float4*)out;
    long vbase = ((long)c << VB_C_SHIFT) + (long)part * VT;
    for (int vl = g; vl < VT; vl += 64) {
        long v = vbase + vl;
        if (v < n_v) {
            int cv = val[vl];
            float inv = 1.0f / (float)(cv > 0 ? cv : 1);
            const float* a = &acc[vl * ACCS + q * 4];
            float4 o;
            o.x = a[0] * inv; o.y = a[1] * inv;
            o.z = a[2] * inv; o.w = a[3] * inv;
            out4[v * 8 + q] = o;
        }
    }
}

// ===================== Fallback: atomic scatter ============================
__global__ void he2v_scatter(const float* __restrict__ x,
                             const int* __restrict__ ids,
                             float* __restrict__ out,
                             float* __restrict__ val,
                             int n_he) {
    long tid = (long)blockIdx.x * blockDim.x + threadIdx.x;
    long stride = (long)gridDim.x * blockDim.x;
    long total = (long)n_he * 8;
    for (long t = tid; t < total; t += stride) {
        int row = (int)(t >> 3);
        int q   = (int)(t & 7);
        int v   = ids[row];
        float4 xv = ((const float4*)x)[(long)row * 8 + q];
        float* dst = out + (long)v * DFEAT + q * 4;
        atomicAdd(dst + 0, xv.x);
        atomicAdd(dst + 1, xv.y);
        atomicAdd(dst + 2, xv.z);
        atomicAdd(dst + 3, xv.w);
        if (q == 0) atomicAdd(val + v, 1.0f);
    }
}

__global__ void he2v_divide(float* __restrict__ out,
                            const float* __restrict__ val,
                            int n_v) {
    long tid = (long)blockIdx.x * blockDim.x + threadIdx.x;
    long total = (long)n_v * 8;
    if (tid >= total) return;
    int v = (int)(tid >> 3);
    float s = val[v];
    if (s < 1.0f) s = 1.0f;
    float4 o = ((float4*)out)[tid];
    o.x /= s; o.y /= s; o.z /= s; o.w /= s;
    ((float4*)out)[tid] = o;
}

extern "C" void kernel_launch(void* const* d_in, const int* in_sizes, int n_in,
                              void* d_out, int out_size, void* d_ws, size_t ws_size,
                              hipStream_t stream) {
    const float* x  = (const float*)d_in[0];
    const int* ids  = (const int*)d_in[1];
    int n_he = in_sizes[0] / DFEAT;
    int n_v  = out_size / DFEAT;
    float* out = (float*)d_out;

    int ncoarse = (n_v + VB_C - 1) / VB_C;
    int nc = ncoarse * CREP;                       // replicated counters
    int nchunks = (n_he + CHUNK - 1) / CHUNK;
    // ws ints: counts[nc] | base[nc+1] | cursor[nc] | pad | pairs[n_he] (int2)
    size_t headInts = ((size_t)3 * nc + 1 + 1) & ~(size_t)1;
    size_t need = headInts * sizeof(int) + (size_t)n_he * sizeof(int2);

    if (ncoarse <= NC_MAX && ws_size >= need) {
        int* counts = (int*)d_ws;
        int* base   = counts + nc;
        int* cursor = base + nc + 1;
        int2* pairs = (int2*)((int*)d_ws + headInts);

        hipMemsetAsync(counts, 0, (size_t)nc * sizeof(int), stream);
        he2v_chist<<<nchunks, 512, 0, stream>>>(ids, counts, n_he);
        he2v_bscan<<<1, 1024, 0, stream>>>(counts, base, cursor, nc);
        he2v_part<<<nchunks, 512, 0, stream>>>(ids, cursor, pairs, n_he);
        he2v_accum<<<ncoarse * 8, 512, 0, stream>>>(x, pairs, base, out, n_v);
    } else {
        float* val = (float*)d_ws;
        hipMemsetAsync(out, 0, (size_t)out_size * sizeof(float), stream);
        hipMemsetAsync(val, 0, (size_t)n_v * sizeof(float), stream);
        he2v_scatter<<<8192, 256, 0, stream>>>(x, ids, out, val, n_he);
        long total = (long)n_v * 8;
        int blocks = (int)((total + 255) / 256);
        he2v_divide<<<blocks, 256, 0, stream>>>(out, val, n_v);
    }
}